// Round 10
// baseline (634.226 us; speedup 1.0000x reference)
//
#include <hip/hip_runtime.h>
#include <hip/hip_bf16.h>

#define NN      262144    // N = B*WIN_IN*NODES
#define EDGES   2097152
#define FEATD   16
#define HIDD    64
#define LSTMH   32
#define BATCH   64
#define WIN     32
#define WOUT    8
#define NCLS    10
#define ROWD    2048      // NODES*FEAT = B*WIN (both 2048)
#define KCHUNKS 8

#define NB      2048      // buckets: node >> 7
#define SH      8         // shards (by blockIdx&7) to cut counter contention
#define CAP     224       // per (shard,bucket) capacity; Poisson(128)+8.5 sigma

// ---- bucketize edges: bdata[(s*NB+b)*CAP + pos] = (r<<8)|(c&127) ----
__global__ void k_bucketize(const int* __restrict__ ei, int* __restrict__ bcnt,
                            int* __restrict__ bdata) {
    int s = blockIdx.x & (SH - 1);
    int stride = gridDim.x * blockDim.x;
    for (int e = blockIdx.x * blockDim.x + threadIdx.x; e < EDGES; e += stride) {
        int r = ei[e];
        int c = ei[EDGES + e];
        int b = c >> 7;
        int pos = atomicAdd(&bcnt[s * NB + b], 1);
        if (pos < CAP) bdata[(size_t)(s * NB + b) * CAP + pos] = (r << 8) | (c & 127);
    }
}

// ---- per-bucket degree -> dinv (LDS histogram, coalesced writes) ----
__global__ void k_bdeg(const int* __restrict__ bcnt, const int* __restrict__ bdata,
                       float* __restrict__ dinv) {
    __shared__ int hist[128];
    int b = blockIdx.x, tid = threadIdx.x;
    if (tid < 128) hist[tid] = 0;
    __syncthreads();
#pragma unroll
    for (int s = 0; s < SH; s++) {
        int len = bcnt[s * NB + b]; if (len > CAP) len = CAP;
        const int* base = bdata + (size_t)(s * NB + b) * CAP;
        for (int i = tid; i < len; i += blockDim.x)
            atomicAdd(&hist[base[i] & 127], 1);
    }
    __syncthreads();
    if (tid < 128) dinv[b * 128 + tid] = rsqrtf((float)hist[tid] + 1.0f);
}

// ---- pre-scale: xs[n][f] = x[n][f] * dinv[n]  (float4 over NN*4) ----
__global__ void k_scale(const float* __restrict__ x, const float* __restrict__ dinv,
                        float* __restrict__ xs) {
    int i = blockIdx.x * blockDim.x + threadIdx.x;   // float4 index
    if (i >= NN * 4) return;
    float d = dinv[i >> 2];
    float4 v = ((const float4*)x)[i];
    v.x *= d; v.y *= d; v.z *= d; v.w *= d;
    ((float4*)xs)[i] = v;
}

// ---- bucket aggregation: cross-iteration software-pipelined gathers ----
// 16 lanes/edge. Two alternating 4-edge register batches: batch B's loads stay
// in flight while batch A's LDS atomics retire (compiler emits vmcnt(4), not 0).
// Indices staged in LDS (lgkmcnt) so index reads never drain the vmcnt queue.
// Edge word = (r<<8)|co ; pad sentinel co=128 lands in dummy acc row 128.
template<int LAYER>
__global__ void __launch_bounds__(256)
k_bagg(const int* __restrict__ bcnt, const int* __restrict__ bdata,
       const float* __restrict__ dinv, const float* __restrict__ xs,
       const float* __restrict__ b2, float* __restrict__ out) {
    __shared__ float acc[129 * FEATD];     // row 128 = pad sink (8.25 KB)
    __shared__ int   sidx[SH * CAP];       // 1792 words (7 KB)
    __shared__ int   seg[SH + 1];
    int b = blockIdx.x, tid = threadIdx.x;
    for (int l = tid; l < 129 * FEATD; l += 256) acc[l] = 0.f;
    if (tid == 0) {
        int ssum = 0; seg[0] = 0;
#pragma unroll
        for (int k = 0; k < SH; k++) {
            int L = bcnt[k * NB + b]; if (L > CAP) L = CAP;
            ssum += L; seg[k + 1] = ssum;
        }
    }
    __syncthreads();
#pragma unroll
    for (int sh = 0; sh < SH; sh++) {
        int o = seg[sh], len = seg[sh + 1] - o;
        const int* base = bdata + (size_t)(sh * NB + b) * CAP;
        for (int i = tid; i < len; i += 256) sidx[o + i] = base[i];
    }
    int total = seg[SH];
    int ptotal = (total + 127) & ~127;
    for (int i = total + tid; i < ptotal; i += 256) sidx[i] = 128;  // pad -> row 128
    __syncthreads();

    int s = tid >> 4;        // edge slot 0..15
    int f = tid & 15;        // feature lane
    int vA0, vA1, vA2, vA3, vB0, vB1, vB2, vB3;
    float tA0, tA1, tA2, tA3, tB0, tB1, tB2, tB3;
#define LOAD_A(off) do { vA0 = sidx[(off) + s];      vA1 = sidx[(off) + 16 + s];        \
                      vA2 = sidx[(off) + 32 + s]; vA3 = sidx[(off) + 48 + s];           \
                      tA0 = xs[(size_t)(vA0 >> 8) * FEATD + f];                          \
                      tA1 = xs[(size_t)(vA1 >> 8) * FEATD + f];                          \
                      tA2 = xs[(size_t)(vA2 >> 8) * FEATD + f];                          \
                      tA3 = xs[(size_t)(vA3 >> 8) * FEATD + f]; } while (0)
#define LOAD_B(off) do { vB0 = sidx[(off) + s];      vB1 = sidx[(off) + 16 + s];        \
                      vB2 = sidx[(off) + 32 + s]; vB3 = sidx[(off) + 48 + s];           \
                      tB0 = xs[(size_t)(vB0 >> 8) * FEATD + f];                          \
                      tB1 = xs[(size_t)(vB1 >> 8) * FEATD + f];                          \
                      tB2 = xs[(size_t)(vB2 >> 8) * FEATD + f];                          \
                      tB3 = xs[(size_t)(vB3 >> 8) * FEATD + f]; } while (0)
#define CONS_A() do { atomicAdd(&acc[(vA0 & 255) * FEATD + f], tA0);                     \
                   atomicAdd(&acc[(vA1 & 255) * FEATD + f], tA1);                        \
                   atomicAdd(&acc[(vA2 & 255) * FEATD + f], tA2);                        \
                   atomicAdd(&acc[(vA3 & 255) * FEATD + f], tA3); } while (0)
#define CONS_B() do { atomicAdd(&acc[(vB0 & 255) * FEATD + f], tB0);                     \
                   atomicAdd(&acc[(vB1 & 255) * FEATD + f], tB1);                        \
                   atomicAdd(&acc[(vB2 & 255) * FEATD + f], tB2);                        \
                   atomicAdd(&acc[(vB3 & 255) * FEATD + f], tB3); } while (0)
    if (total > 0) {
        LOAD_A(0);
        int phase = 0;
        for (int off = 64; off < ptotal; off += 64) {
            if (!phase) { LOAD_B(off); CONS_A(); }
            else        { LOAD_A(off); CONS_B(); }
            phase ^= 1;
        }
        if (!phase) { CONS_A(); } else { CONS_B(); }
    }
    __syncthreads();
    for (int l = tid; l < 128 * FEATD; l += 256) {
        int n = b * 128 + (l >> 4);
        int ff = l & 15;
        float dc = dinv[n];
        float v = (acc[l] + xs[(size_t)n * FEATD + ff]) * dc;  // xs holds src*dinv
        if (LAYER == 2) v = fmaxf(v + b2[ff], 0.f);
        out[(size_t)b * (128 * FEATD) + l] = v;
    }
#undef LOAD_A
#undef LOAD_B
#undef CONS_A
#undef CONS_B
}

// ---- fused MLP: hid = relu(in1@W1+b1) ; t2s = (hid@W2) * dinv  (pre-scaled) ----
__global__ void k_gcnmlp(const float* __restrict__ in1, const float* __restrict__ dinv,
                         const float* __restrict__ W1, const float* __restrict__ b1,
                         const float* __restrict__ W2, float* __restrict__ t2) {
    __shared__ float sW1[FEATD * HIDD];
    __shared__ float sW2[HIDD * FEATD];
    __shared__ float sb1[HIDD];
    for (int l = threadIdx.x; l < FEATD * HIDD; l += blockDim.x) {
        sW1[l] = W1[l];
        sW2[l] = W2[l];
    }
    if (threadIdx.x < HIDD) sb1[threadIdx.x] = b1[threadIdx.x];
    __syncthreads();
    int n = blockIdx.x * blockDim.x + threadIdx.x;
    if (n >= NN) return;
    float in[FEATD];
    const float4* ax = (const float4*)(in1 + (size_t)n * FEATD);
#pragma unroll
    for (int q = 0; q < 4; q++) {
        float4 a = ax[q];
        in[q * 4 + 0] = a.x; in[q * 4 + 1] = a.y; in[q * 4 + 2] = a.z; in[q * 4 + 3] = a.w;
    }
    float out[FEATD];
#pragma unroll
    for (int c = 0; c < FEATD; c++) out[c] = 0.f;
#pragma unroll 8
    for (int j = 0; j < HIDD; j++) {
        float h = sb1[j];
#pragma unroll
        for (int f = 0; f < FEATD; f++) h += in[f] * sW1[f * HIDD + j];
        h = fmaxf(h, 0.f);
#pragma unroll
        for (int c = 0; c < FEATD; c++) out[c] += h * sW2[j * FEATD + c];
    }
    float dn = dinv[n];
    float4* o = (float4*)(t2 + (size_t)n * FEATD);
    o[0] = make_float4(out[0] * dn, out[1] * dn, out[2] * dn, out[3] * dn);
    o[1] = make_float4(out[4] * dn, out[5] * dn, out[6] * dn, out[7] * dn);
    o[2] = make_float4(out[8] * dn, out[9] * dn, out[10] * dn, out[11] * dn);
    o[3] = make_float4(out[12] * dn, out[13] * dn, out[14] * dn, out[15] * dn);
}

// ---- LSTM input GEMM: gxp[p][r][j] = sum_{k in chunk p} A[r][k]*Wih[j][k] ----
#define KT 32
__global__ void k_gemmA(const float* __restrict__ A, const float* __restrict__ Wih,
                        float* __restrict__ gxp) {
    __shared__ float As[64][KT + 1];
    __shared__ float Bs[128][KT + 1];
    int tid = threadIdx.x;
    int tx = tid & 15, ty = tid >> 4;
    float acc[4][8];
#pragma unroll
    for (int i = 0; i < 4; i++)
#pragma unroll
        for (int j = 0; j < 8; j++) acc[i][j] = 0.f;
    int row0 = blockIdx.x * 64;
    int k0 = blockIdx.y * (ROWD / KCHUNKS);
    for (int kk = 0; kk < ROWD / KCHUNKS; kk += KT) {
        for (int l = tid; l < 64 * KT / 4; l += 256) {
            int rr = l >> 3;
            int cc = (l & 7) * 4;
            float4 v = *(const float4*)&A[(size_t)(row0 + rr) * ROWD + k0 + kk + cc];
            As[rr][cc + 0] = v.x; As[rr][cc + 1] = v.y; As[rr][cc + 2] = v.z; As[rr][cc + 3] = v.w;
        }
        for (int l = tid; l < 128 * KT / 4; l += 256) {
            int rr = l >> 3;
            int cc = (l & 7) * 4;
            float4 v = *(const float4*)&Wih[(size_t)rr * ROWD + k0 + kk + cc];
            Bs[rr][cc + 0] = v.x; Bs[rr][cc + 1] = v.y; Bs[rr][cc + 2] = v.z; Bs[rr][cc + 3] = v.w;
        }
        __syncthreads();
#pragma unroll
        for (int k = 0; k < KT; k++) {
            float a[4], bb[8];
#pragma unroll
            for (int i = 0; i < 4; i++) a[i] = As[ty * 4 + i][k];
#pragma unroll
            for (int j = 0; j < 8; j++) bb[j] = Bs[tx * 8 + j][k];
#pragma unroll
            for (int i = 0; i < 4; i++)
#pragma unroll
                for (int j = 0; j < 8; j++) acc[i][j] += a[i] * bb[j];
        }
        __syncthreads();
    }
    float* outp = gxp + (size_t)blockIdx.y * (ROWD * 128);
#pragma unroll
    for (int i = 0; i < 4; i++)
#pragma unroll
        for (int j = 0; j < 8; j++)
            outp[(size_t)(row0 + ty * 4 + i) * 128 + tx * 8 + j] = acc[i][j];
}

// ---- LSTM recurrence: one block per batch element ----
__global__ void k_lstm(const float* __restrict__ gxp, const float* __restrict__ Whh,
                       const float* __restrict__ bih, const float* __restrict__ bhh,
                       float* __restrict__ hseq) {
    __shared__ float sWhhT[LSTMH][4 * LSTMH];   // [k][j] = Whh[j][k]
    __shared__ float sh[LSTMH], sc[LSTMH], sg[4 * LSTMH];
    int b = blockIdx.x, j = threadIdx.x;
    for (int l = j; l < 4 * LSTMH * LSTMH; l += 4 * LSTMH) {
        int r = l >> 5, k = l & 31;
        sWhhT[k][r] = Whh[l];
    }
    float bias = bih[j] + bhh[j];
    if (j < LSTMH) { sh[j] = 0.f; sc[j] = 0.f; }
    __syncthreads();
    for (int t = 0; t < WIN; t++) {
        const float* g0 = gxp + (size_t)(b * WIN + t) * 128 + j;
        float g = bias;
#pragma unroll
        for (int p = 0; p < KCHUNKS; p++) g += g0[(size_t)p * ROWD * 128];
#pragma unroll
        for (int k = 0; k < LSTMH; k++) g += sWhhT[k][j] * sh[k];
        sg[j] = g;
        __syncthreads();
        if (j < LSTMH) {
            float ig = sg[j], fg = sg[32 + j], gg = sg[64 + j], og = sg[96 + j];
            float c = sc[j];
            float si = 1.f / (1.f + __expf(-ig));
            float sf = 1.f / (1.f + __expf(-fg));
            float so = 1.f / (1.f + __expf(-og));
            c = sf * c + si * tanhf(gg);
            float h = so * tanhf(c);
            sc[j] = c; sh[j] = h;
            if (t >= WIN - WOUT)
                hseq[(size_t)(b * WOUT + (t - (WIN - WOUT))) * LSTMH + j] = h;
        }
        __syncthreads();
    }
}

// ---- FC head: (512 rows) 32 -> 16 relu -> 10 ----
__global__ void k_fc(const float* __restrict__ hseq, const float* __restrict__ Wfc1,
                     const float* __restrict__ bfc1, const float* __restrict__ Wfc2,
                     const float* __restrict__ bfc2, float* __restrict__ out) {
    __shared__ float sW1[16 * 32], sb1[16], sW2[10 * 16], sb2[10];
    int tid = threadIdx.x;
    for (int l = tid; l < 16 * 32; l += blockDim.x) sW1[l] = Wfc1[l];
    if (tid < 16) sb1[tid] = bfc1[tid];
    for (int l = tid; l < 160; l += blockDim.x) sW2[l] = Wfc2[l];
    if (tid < 10) sb2[tid] = bfc2[tid];
    __syncthreads();
    int r = blockIdx.x * blockDim.x + tid;
    if (r >= BATCH * WOUT) return;
    float h[32];
#pragma unroll
    for (int k = 0; k < 32; k++) h[k] = hseq[(size_t)r * 32 + k];
    float hid[16];
#pragma unroll
    for (int j = 0; j < 16; j++) {
        float v = sb1[j];
#pragma unroll
        for (int k = 0; k < 32; k++) v += sW1[j * 32 + k] * h[k];
        hid[j] = fmaxf(v, 0.f);
    }
#pragma unroll
    for (int c = 0; c < NCLS; c++) {
        float v = sb2[c];
#pragma unroll
        for (int j = 0; j < 16; j++) v += sW2[c * 16 + j] * hid[j];
        out[(size_t)r * NCLS + c] = v;
    }
}

extern "C" void kernel_launch(void* const* d_in, const int* in_sizes, int n_in,
                              void* d_out, int out_size, void* d_ws, size_t ws_size,
                              hipStream_t stream) {
    const float* x    = (const float*)d_in[0];
    const int*   ei   = (const int*)d_in[1];
    const float* W1   = (const float*)d_in[2];
    const float* b1   = (const float*)d_in[3];
    const float* W2   = (const float*)d_in[4];
    const float* b2   = (const float*)d_in[5];
    const float* Wih  = (const float*)d_in[6];
    const float* Whh  = (const float*)d_in[7];
    const float* bih  = (const float*)d_in[8];
    const float* bhh  = (const float*)d_in[9];
    const float* Wfc1 = (const float*)d_in[10];
    const float* bfc1 = (const float*)d_in[11];
    const float* Wfc2 = (const float*)d_in[12];
    const float* bfc2 = (const float*)d_in[13];
    float* out = (float*)d_out;

    float* ws   = (float*)d_ws;
    float* dinv = ws;                                  // NN floats (1 MB)
    int*   bcnt = (int*)(dinv + NN);                   // SH*NB ints (64 KB)
    int*   bdata= bcnt + SH * NB;                      // SH*NB*CAP ints (14 MB)
    float* bufA = (float*)(bdata + (size_t)SH * NB * CAP); // NN*16 (16 MB)
    float* bufB = bufA + (size_t)NN * FEATD;           // NN*16 (16 MB)
    float* hseq = bufB + (size_t)NN * FEATD;           // 64*8*32

    (void)hipMemsetAsync(bcnt, 0, SH * NB * sizeof(int), stream);
    k_bucketize<<<2048, 256, 0, stream>>>(ei, bcnt, bdata);
    k_bdeg<<<NB, 256, 0, stream>>>(bcnt, bdata, dinv);

    // xs = x * dinv -> bufB (bufB free until k_gcnmlp writes it)
    k_scale<<<NN * 4 / 256, 256, 0, stream>>>(x, dinv, bufB);
    k_bagg<1><<<NB, 256, 0, stream>>>(bcnt, bdata, dinv, bufB, b2, bufA);
    k_gcnmlp<<<NN / 256, 256, 0, stream>>>(bufA, dinv, W1, b1, W2, bufB);  // t2s (pre-scaled)
    k_bagg<2><<<NB, 256, 0, stream>>>(bcnt, bdata, dinv, bufB, b2, bufA);  // h2

    dim3 gg(ROWD / 64, KCHUNKS);
    k_gemmA<<<gg, 256, 0, stream>>>(bufA, Wih, bufB);
    k_lstm<<<BATCH, 128, 0, stream>>>(bufB, Whh, bih, bhh, hseq);
    k_fc<<<2, 256, 0, stream>>>(hseq, Wfc1, bfc1, Wfc2, bfc2, out);
}

// Round 11
// 479.018 us; speedup vs baseline: 1.3240x; 1.3240x over previous
//
#include <hip/hip_runtime.h>
#include <hip/hip_bf16.h>

#define NN      262144    // N = B*WIN_IN*NODES
#define EDGES   2097152
#define FEATD   16
#define HIDD    64
#define LSTMH   32
#define BATCH   64
#define WIN     32
#define WOUT    8
#define NCLS    10
#define ROWD    2048      // NODES*FEAT = B*WIN (both 2048)
#define KCHUNKS 8

// ---- degree histogram: cnt[col] += 1 per edge (int atomics) ----
__global__ void k_deg(const int* __restrict__ ei, int* __restrict__ cnt) {
    int stride = gridDim.x * blockDim.x;
    for (int e = blockIdx.x * blockDim.x + threadIdx.x; e < EDGES; e += stride)
        atomicAdd(&cnt[ei[EDGES + e]], 1);
}

// ---- dinv[i] = rsqrt(cnt+1) ----
__global__ void k_dinv(const int* __restrict__ cnt, float* __restrict__ dinv) {
    int i = blockIdx.x * blockDim.x + threadIdx.x;
    if (i < NN) dinv[i] = rsqrtf((float)cnt[i] + 1.0f);
}

// ---- pre-scale: xs[n][f] = x[n][f] * dinv[n]  (float4 over NN*4) ----
__global__ void k_scale(const float* __restrict__ x, const float* __restrict__ dinv,
                        float* __restrict__ xs) {
    int i = blockIdx.x * blockDim.x + threadIdx.x;   // float4 index
    if (i >= NN * 4) return;
    float d = dinv[i >> 2];
    float4 v = ((const float4*)x)[i];
    v.x *= d; v.y *= d; v.z *= d; v.w *= d;
    ((float4*)xs)[i] = v;
}

// ---- edge aggregation (round-1 proven structure): agg[c][f] += xs[r][f] ----
// thread = (edge, feat): 33.5M independent items, no barriers, fire-and-forget
// global atomics. 16 lanes share one edge -> 64B coalesced gather.
__global__ void k_agg(const int* __restrict__ ei, const float* __restrict__ xs,
                      float* __restrict__ agg) {
    int stride = gridDim.x * blockDim.x;
    const int total = EDGES * FEATD;
    for (int t = blockIdx.x * blockDim.x + threadIdx.x; t < total; t += stride) {
        int e = t >> 4;
        int f = t & 15;
        int r = ei[e];
        int c = ei[EDGES + e];
        atomicAdd(&agg[(size_t)c * FEATD + f], xs[(size_t)r * FEATD + f]);
    }
}

// ---- combine: out = (agg + selfs) * dinv  (+b2, relu for layer 2) ----
// elementwise coalesced float4; out may alias agg.
template<int LAYER>
__global__ void k_combine(const float* __restrict__ agg, const float* __restrict__ selfs,
                          const float* __restrict__ dinv, const float* __restrict__ b2,
                          float* __restrict__ out) {
    int i = blockIdx.x * blockDim.x + threadIdx.x;   // float4 index, NN*4 total
    if (i >= NN * 4) return;
    int node = i >> 2, q = i & 3;
    float d = dinv[node];
    float4 a = ((const float4*)agg)[i];
    float4 s = ((const float4*)selfs)[i];
    float4 r;
    r.x = (a.x + s.x) * d;
    r.y = (a.y + s.y) * d;
    r.z = (a.z + s.z) * d;
    r.w = (a.w + s.w) * d;
    if (LAYER == 2) {
        float4 bb = ((const float4*)b2)[q];
        r.x = fmaxf(r.x + bb.x, 0.f);
        r.y = fmaxf(r.y + bb.y, 0.f);
        r.z = fmaxf(r.z + bb.z, 0.f);
        r.w = fmaxf(r.w + bb.w, 0.f);
    }
    ((float4*)out)[i] = r;
}

// ---- fused MLP: hid = relu(in1@W1+b1) ; t2s = (hid@W2) * dinv  (pre-scaled) ----
__global__ void k_gcnmlp(const float* __restrict__ in1, const float* __restrict__ dinv,
                         const float* __restrict__ W1, const float* __restrict__ b1,
                         const float* __restrict__ W2, float* __restrict__ t2) {
    __shared__ float sW1[FEATD * HIDD];
    __shared__ float sW2[HIDD * FEATD];
    __shared__ float sb1[HIDD];
    for (int l = threadIdx.x; l < FEATD * HIDD; l += blockDim.x) {
        sW1[l] = W1[l];
        sW2[l] = W2[l];
    }
    if (threadIdx.x < HIDD) sb1[threadIdx.x] = b1[threadIdx.x];
    __syncthreads();
    int n = blockIdx.x * blockDim.x + threadIdx.x;
    if (n >= NN) return;
    float in[FEATD];
    const float4* ax = (const float4*)(in1 + (size_t)n * FEATD);
#pragma unroll
    for (int q = 0; q < 4; q++) {
        float4 a = ax[q];
        in[q * 4 + 0] = a.x; in[q * 4 + 1] = a.y; in[q * 4 + 2] = a.z; in[q * 4 + 3] = a.w;
    }
    float out[FEATD];
#pragma unroll
    for (int c = 0; c < FEATD; c++) out[c] = 0.f;
#pragma unroll 8
    for (int j = 0; j < HIDD; j++) {
        float h = sb1[j];
#pragma unroll
        for (int f = 0; f < FEATD; f++) h += in[f] * sW1[f * HIDD + j];
        h = fmaxf(h, 0.f);
#pragma unroll
        for (int c = 0; c < FEATD; c++) out[c] += h * sW2[j * FEATD + c];
    }
    float dn = dinv[n];
    float4* o = (float4*)(t2 + (size_t)n * FEATD);
    o[0] = make_float4(out[0] * dn, out[1] * dn, out[2] * dn, out[3] * dn);
    o[1] = make_float4(out[4] * dn, out[5] * dn, out[6] * dn, out[7] * dn);
    o[2] = make_float4(out[8] * dn, out[9] * dn, out[10] * dn, out[11] * dn);
    o[3] = make_float4(out[12] * dn, out[13] * dn, out[14] * dn, out[15] * dn);
}

// ---- LSTM input GEMM: gxp[p][r][j] = sum_{k in chunk p} A[r][k]*Wih[j][k] ----
#define KT 32
__global__ void k_gemmA(const float* __restrict__ A, const float* __restrict__ Wih,
                        float* __restrict__ gxp) {
    __shared__ float As[64][KT + 1];
    __shared__ float Bs[128][KT + 1];
    int tid = threadIdx.x;
    int tx = tid & 15, ty = tid >> 4;
    float acc[4][8];
#pragma unroll
    for (int i = 0; i < 4; i++)
#pragma unroll
        for (int j = 0; j < 8; j++) acc[i][j] = 0.f;
    int row0 = blockIdx.x * 64;
    int k0 = blockIdx.y * (ROWD / KCHUNKS);
    for (int kk = 0; kk < ROWD / KCHUNKS; kk += KT) {
        for (int l = tid; l < 64 * KT / 4; l += 256) {
            int rr = l >> 3;
            int cc = (l & 7) * 4;
            float4 v = *(const float4*)&A[(size_t)(row0 + rr) * ROWD + k0 + kk + cc];
            As[rr][cc + 0] = v.x; As[rr][cc + 1] = v.y; As[rr][cc + 2] = v.z; As[rr][cc + 3] = v.w;
        }
        for (int l = tid; l < 128 * KT / 4; l += 256) {
            int rr = l >> 3;
            int cc = (l & 7) * 4;
            float4 v = *(const float4*)&Wih[(size_t)rr * ROWD + k0 + kk + cc];
            Bs[rr][cc + 0] = v.x; Bs[rr][cc + 1] = v.y; Bs[rr][cc + 2] = v.z; Bs[rr][cc + 3] = v.w;
        }
        __syncthreads();
#pragma unroll
        for (int k = 0; k < KT; k++) {
            float a[4], bb[8];
#pragma unroll
            for (int i = 0; i < 4; i++) a[i] = As[ty * 4 + i][k];
#pragma unroll
            for (int j = 0; j < 8; j++) bb[j] = Bs[tx * 8 + j][k];
#pragma unroll
            for (int i = 0; i < 4; i++)
#pragma unroll
                for (int j = 0; j < 8; j++) acc[i][j] += a[i] * bb[j];
        }
        __syncthreads();
    }
    float* outp = gxp + (size_t)blockIdx.y * (ROWD * 128);
#pragma unroll
    for (int i = 0; i < 4; i++)
#pragma unroll
        for (int j = 0; j < 8; j++)
            outp[(size_t)(row0 + ty * 4 + i) * 128 + tx * 8 + j] = acc[i][j];
}

// ---- LSTM recurrence: one block per batch element ----
__global__ void k_lstm(const float* __restrict__ gxp, const float* __restrict__ Whh,
                       const float* __restrict__ bih, const float* __restrict__ bhh,
                       float* __restrict__ hseq) {
    __shared__ float sWhhT[LSTMH][4 * LSTMH];   // [k][j] = Whh[j][k]
    __shared__ float sh[LSTMH], sc[LSTMH], sg[4 * LSTMH];
    int b = blockIdx.x, j = threadIdx.x;
    for (int l = j; l < 4 * LSTMH * LSTMH; l += 4 * LSTMH) {
        int r = l >> 5, k = l & 31;
        sWhhT[k][r] = Whh[l];
    }
    float bias = bih[j] + bhh[j];
    if (j < LSTMH) { sh[j] = 0.f; sc[j] = 0.f; }
    __syncthreads();
    for (int t = 0; t < WIN; t++) {
        const float* g0 = gxp + (size_t)(b * WIN + t) * 128 + j;
        float g = bias;
#pragma unroll
        for (int p = 0; p < KCHUNKS; p++) g += g0[(size_t)p * ROWD * 128];
#pragma unroll
        for (int k = 0; k < LSTMH; k++) g += sWhhT[k][j] * sh[k];
        sg[j] = g;
        __syncthreads();
        if (j < LSTMH) {
            float ig = sg[j], fg = sg[32 + j], gg = sg[64 + j], og = sg[96 + j];
            float c = sc[j];
            float si = 1.f / (1.f + __expf(-ig));
            float sf = 1.f / (1.f + __expf(-fg));
            float so = 1.f / (1.f + __expf(-og));
            c = sf * c + si * tanhf(gg);
            float h = so * tanhf(c);
            sc[j] = c; sh[j] = h;
            if (t >= WIN - WOUT)
                hseq[(size_t)(b * WOUT + (t - (WIN - WOUT))) * LSTMH + j] = h;
        }
        __syncthreads();
    }
}

// ---- FC head: (512 rows) 32 -> 16 relu -> 10 ----
__global__ void k_fc(const float* __restrict__ hseq, const float* __restrict__ Wfc1,
                     const float* __restrict__ bfc1, const float* __restrict__ Wfc2,
                     const float* __restrict__ bfc2, float* __restrict__ out) {
    __shared__ float sW1[16 * 32], sb1[16], sW2[10 * 16], sb2[10];
    int tid = threadIdx.x;
    for (int l = tid; l < 16 * 32; l += blockDim.x) sW1[l] = Wfc1[l];
    if (tid < 16) sb1[tid] = bfc1[tid];
    for (int l = tid; l < 160; l += blockDim.x) sW2[l] = Wfc2[l];
    if (tid < 10) sb2[tid] = bfc2[tid];
    __syncthreads();
    int r = blockIdx.x * blockDim.x + tid;
    if (r >= BATCH * WOUT) return;
    float h[32];
#pragma unroll
    for (int k = 0; k < 32; k++) h[k] = hseq[(size_t)r * 32 + k];
    float hid[16];
#pragma unroll
    for (int j = 0; j < 16; j++) {
        float v = sb1[j];
#pragma unroll
        for (int k = 0; k < 32; k++) v += sW1[j * 32 + k] * h[k];
        hid[j] = fmaxf(v, 0.f);
    }
#pragma unroll
    for (int c = 0; c < NCLS; c++) {
        float v = sb2[c];
#pragma unroll
        for (int j = 0; j < 16; j++) v += sW2[c * 16 + j] * hid[j];
        out[(size_t)r * NCLS + c] = v;
    }
}

extern "C" void kernel_launch(void* const* d_in, const int* in_sizes, int n_in,
                              void* d_out, int out_size, void* d_ws, size_t ws_size,
                              hipStream_t stream) {
    const float* x    = (const float*)d_in[0];
    const int*   ei   = (const int*)d_in[1];
    const float* W1   = (const float*)d_in[2];
    const float* b1   = (const float*)d_in[3];
    const float* W2   = (const float*)d_in[4];
    const float* b2   = (const float*)d_in[5];
    const float* Wih  = (const float*)d_in[6];
    const float* Whh  = (const float*)d_in[7];
    const float* bih  = (const float*)d_in[8];
    const float* bhh  = (const float*)d_in[9];
    const float* Wfc1 = (const float*)d_in[10];
    const float* bfc1 = (const float*)d_in[11];
    const float* Wfc2 = (const float*)d_in[12];
    const float* bfc2 = (const float*)d_in[13];
    float* out = (float*)d_out;

    float* ws   = (float*)d_ws;
    float* dinv = ws;                                  // NN floats (1 MB)
    int*   cnt  = (int*)(dinv + NN);                   // NN ints (1 MB)
    float* bufA = (float*)(cnt + NN);                  // NN*16 (16 MB): agg/in1/h2
    float* bufB = bufA + (size_t)NN * FEATD;           // NN*16 (16 MB): xs/t2s/gxp
    float* hseq = bufB + (size_t)NN * FEATD;           // 64*8*32

    // zero cnt + agg in one contiguous memset
    (void)hipMemsetAsync(cnt, 0, (size_t)(NN + NN * FEATD) * sizeof(float), stream);
    k_deg<<<2048, 256, 0, stream>>>(ei, cnt);
    k_dinv<<<NN / 256, 256, 0, stream>>>(cnt, dinv);
    k_scale<<<NN * 4 / 256, 256, 0, stream>>>(x, dinv, bufB);      // xs

    k_agg<<<8192, 256, 0, stream>>>(ei, bufB, bufA);               // agg1
    k_combine<1><<<NN * 4 / 256, 256, 0, stream>>>(bufA, bufB, dinv, b2, bufA);  // in1
    k_gcnmlp<<<NN / 256, 256, 0, stream>>>(bufA, dinv, W1, b1, W2, bufB);        // t2s

    (void)hipMemsetAsync(bufA, 0, (size_t)NN * FEATD * sizeof(float), stream);
    k_agg<<<8192, 256, 0, stream>>>(ei, bufB, bufA);               // agg2
    k_combine<2><<<NN * 4 / 256, 256, 0, stream>>>(bufA, bufB, dinv, b2, bufA);  // h2

    dim3 gg(ROWD / 64, KCHUNKS);
    k_gemmA<<<gg, 256, 0, stream>>>(bufA, Wih, bufB);
    k_lstm<<<BATCH, 128, 0, stream>>>(bufB, Whh, bih, bhh, hseq);
    k_fc<<<2, 256, 0, stream>>>(hseq, Wfc1, bfc1, Wfc2, bfc2, out);
}